// Round 1
// baseline (309.430 us; speedup 1.0000x reference)
//
#include <hip/hip_runtime.h>
#include <math.h>

#define B_ 2
#define L_ 2048
#define C_ 768
#define H_ 12
#define D_ 64
#define M_ (B_ * L_)          // 4096
#define MAXLOG 4.605170185988091f   // log(100)

typedef __bf16 bf16;
typedef __bf16 bf16x4 __attribute__((ext_vector_type(4)));
typedef __bf16 bf16x8 __attribute__((ext_vector_type(8)));
typedef float  f32x4  __attribute__((ext_vector_type(4)));
typedef short  s16x4  __attribute__((ext_vector_type(4)));

// workspace element counts
#define SZ_  ((size_t)B_ * H_ * L_ * D_)   // 3,145,728 (q,k,vt each)
#define MC_  ((size_t)M_ * C_)             // 3,145,728 (x / ao)
#define WQ_  ((size_t)3 * C_ * C_)         // 1,769,472 (W_qkv)
#define WP_  ((size_t)C_ * C_)             //   589,824 (W_proj)

// K=16 bf16 MFMA: acc layout of 16x16x32 (row=4*quad+reg) == B-frag layout here,
// which is what lets P^T go from accumulator straight into PV with no transpose.
static __device__ __forceinline__ f32x4 mfma16(bf16x4 a, bf16x4 b, f32x4 c) {
#if __has_builtin(__builtin_amdgcn_mfma_f32_16x16x16_bf16)
    return __builtin_amdgcn_mfma_f32_16x16x16_bf16(a, b, c, 0, 0, 0);
#elif __has_builtin(__builtin_amdgcn_mfma_f32_16x16x16bf16_1k)
    return __builtin_amdgcn_mfma_f32_16x16x16bf16_1k(*(s16x4*)&a, *(s16x4*)&b, c, 0, 0, 0);
#else
    f32x4 d;
    asm("v_mfma_f32_16x16x16_bf16 %0, %1, %2, %3" : "=v"(d) : "v"(a), "v"(b), "v"(c));
    return d;
#endif
}

// ---------------------------------------------------------------------------
// Kernel 0: fused prep. Zero-fill of qb..aol removed (all fully overwritten
// by qkv_mfma / flash_mfma) — saves ~25 MB of dead stores.
// ---------------------------------------------------------------------------
__global__ __launch_bounds__(256) void prep(
    const float4* __restrict__ x, const float4* __restrict__ Wq,
    const float4* __restrict__ Wp,
    bf16* __restrict__ xb, bf16* __restrict__ wqb,
    bf16* __restrict__ Wh, bf16* __restrict__ Wl)
{
    const int X4 = (int)(MC_ / 4);
    const int W4 = (int)(WQ_ / 4);
    const int S4 = (int)(WP_ / 4);
    const int total = X4 + W4 + S4;

    const int i0 = blockIdx.x * 256 + threadIdx.x;
    const int stride = gridDim.x * 256;
    for (int i = i0; i < total; i += stride) {
        if (i < X4) {
            const float4 v = x[i];
            bf16x4 o; o[0]=(bf16)v.x; o[1]=(bf16)v.y; o[2]=(bf16)v.z; o[3]=(bf16)v.w;
            *(bf16x4*)&xb[(size_t)i * 4] = o;
        } else if (i < X4 + W4) {
            const int j = i - X4;
            const float4 v = Wq[j];
            bf16x4 o; o[0]=(bf16)v.x; o[1]=(bf16)v.y; o[2]=(bf16)v.z; o[3]=(bf16)v.w;
            *(bf16x4*)&wqb[(size_t)j * 4] = o;
        } else {
            const int j = i - X4 - W4;
            const float4 v = Wp[j];
            bf16x4 h, l;
            h[0]=(bf16)v.x; l[0]=(bf16)(v.x-(float)h[0]);
            h[1]=(bf16)v.y; l[1]=(bf16)(v.y-(float)h[1]);
            h[2]=(bf16)v.z; l[2]=(bf16)(v.z-(float)h[2]);
            h[3]=(bf16)v.w; l[3]=(bf16)(v.w-(float)h[3]);
            *(bf16x4*)&Wh[(size_t)j * 4] = h;
            *(bf16x4*)&Wl[(size_t)j * 4] = l;
        }
    }
}

// ---------------------------------------------------------------------------
// Kernel 1: QKV GEMM (unchanged).
// ---------------------------------------------------------------------------
__global__ __launch_bounds__(256) void qkv_mfma(
    const bf16* __restrict__ A, const bf16* __restrict__ W,
    const float* __restrict__ bias, const float* __restrict__ sml,
    bf16* __restrict__ qb, bf16* __restrict__ kb, bf16* __restrict__ vtb)
{
    __shared__ __align__(16) bf16 As[128][72];
    __shared__ __align__(16) bf16 Bs[64][72];

    const int t    = threadIdx.x;
    const int w    = t >> 6;
    const int lane = t & 63;
    const int quad = lane >> 4;
    const int c    = lane & 15;
    const int m0   = blockIdx.x * 128;
    const int n0   = blockIdx.y * 64;

    const int r0 = t >> 3;
    const int cg = (t & 7) * 8;

    f32x4 acc[2][4];
    #pragma unroll
    for (int mt = 0; mt < 2; ++mt)
        #pragma unroll
        for (int nt = 0; nt < 4; ++nt) acc[mt][nt] = (f32x4){0.f,0.f,0.f,0.f};

    bf16x8 areg[4], breg[2];
    #pragma unroll
    for (int p = 0; p < 4; ++p)
        areg[p] = *(const bf16x8*)&A[(size_t)(m0 + r0 + 32 * p) * C_ + cg];
    #pragma unroll
    for (int p = 0; p < 2; ++p)
        breg[p] = *(const bf16x8*)&W[(size_t)(n0 + r0 + 32 * p) * C_ + cg];

    for (int kt = 0; kt < C_; kt += 64) {
        __syncthreads();
        #pragma unroll
        for (int p = 0; p < 4; ++p) *(bf16x8*)&As[r0 + 32 * p][cg] = areg[p];
        #pragma unroll
        for (int p = 0; p < 2; ++p) *(bf16x8*)&Bs[r0 + 32 * p][cg] = breg[p];

        const int kt2 = kt + 64;
        if (kt2 < C_) {
            #pragma unroll
            for (int p = 0; p < 4; ++p)
                areg[p] = *(const bf16x8*)&A[(size_t)(m0 + r0 + 32 * p) * C_ + kt2 + cg];
            #pragma unroll
            for (int p = 0; p < 2; ++p)
                breg[p] = *(const bf16x8*)&W[(size_t)(n0 + r0 + 32 * p) * C_ + kt2 + cg];
        }
        __syncthreads();

        #pragma unroll
        for (int ks = 0; ks < 2; ++ks) {
            #pragma unroll
            for (int mt = 0; mt < 2; ++mt) {
                const bf16x8 a = *(const bf16x8*)&As[w * 32 + mt * 16 + c][ks * 32 + quad * 8];
                #pragma unroll
                for (int nt = 0; nt < 4; ++nt) {
                    const bf16x8 b = *(const bf16x8*)&Bs[nt * 16 + c][ks * 32 + quad * 8];
                    acc[mt][nt] = __builtin_amdgcn_mfma_f32_16x16x32_bf16(a, b, acc[mt][nt], 0, 0, 0);
                }
            }
        }
    }

    const int three = blockIdx.y / H_;
    const int h     = blockIdx.y % H_;
    const int bidx  = m0 >> 11;
    const int l0    = (m0 & (L_ - 1)) + w * 32;

    if (three < 2) {
        bf16* dst = (three == 0) ? qb : kb;
        const float scale = (three == 0) ? expf(fminf(sml[h], MAXLOG)) : 1.0f;
        #pragma unroll
        for (int mt = 0; mt < 2; ++mt) {
            float val[4][4];
            float ss[4] = {0.f, 0.f, 0.f, 0.f};
            #pragma unroll
            for (int nt = 0; nt < 4; ++nt) {
                const float bb = bias[n0 + nt * 16 + c];
                #pragma unroll
                for (int reg = 0; reg < 4; ++reg) {
                    const float v = acc[mt][nt][reg] + bb;
                    val[nt][reg] = v;
                    ss[reg] += v * v;
                }
            }
            #pragma unroll
            for (int reg = 0; reg < 4; ++reg) {
                float s = ss[reg];
                #pragma unroll
                for (int off = 1; off < 16; off <<= 1) s += __shfl_xor(s, off, 16);
                const float inv = scale / fmaxf(sqrtf(s), 1e-12f);
                const int l = l0 + mt * 16 + quad * 4 + reg;
                #pragma unroll
                for (int nt = 0; nt < 4; ++nt)
                    dst[((size_t)(bidx * H_ + h) * L_ + l) * D_ + nt * 16 + c] =
                        (bf16)(val[nt][reg] * inv);
            }
        }
    } else {
        #pragma unroll
        for (int mt = 0; mt < 2; ++mt)
            #pragma unroll
            for (int nt = 0; nt < 4; ++nt) {
                const int d = nt * 16 + c;
                const float bb = bias[n0 + d];
                const int l = l0 + mt * 16 + quad * 4;
                bf16x4 o;
                #pragma unroll
                for (int reg = 0; reg < 4; ++reg) o[reg] = (bf16)(acc[mt][nt][reg] + bb);
                *(bf16x4*)&vtb[((size_t)(bidx * H_ + h) * D_ + d) * L_ + l] = o;
            }
    }
}

// ---------------------------------------------------------------------------
// Kernel 2: flash attention v6 — barrier-free main loop.
//   Block = (64 q, bh), 4 waves. Wave (wq,wk) owns a (32 q x 1024 k) quadrant:
//   S^T = K·Q^T via 16x16x32 MFMA (bias as the C operand, float4 loads),
//   exp in-register, P^T accumulator == B-frag of 16x16x16 MFMA -> PV with
//   zero transpose/LDS. K/V/bias fragments read straight from global
//   (L2-resident, 32x q-block reuse; wq-pairs share K/V via L1).
//   Single barrier at the end merges the two k-halves (fixed-FMAX softmax
//   => O and l are purely additive).
// ---------------------------------------------------------------------------
__global__ __launch_bounds__(256, 2) void flash_mfma(
    const bf16* __restrict__ q, const bf16* __restrict__ k,
    const bf16* __restrict__ vt, const float* __restrict__ bias,
    const float* __restrict__ sml,
    bf16* __restrict__ aoh, bf16* __restrict__ aol)
{
    __shared__ __align__(16) float OfT[2][4][2][64][4];  // [wq][dt][qt][lane][reg] 16 KB
    __shared__ float lfs[2][2][16];                      // [wq][qt][c]

    const int t    = threadIdx.x;
    const int w    = t >> 6;
    const int lane = t & 63;
    const int quad = lane >> 4;
    const int c    = lane & 15;
    const int wq   = w >> 1;        // q-half: 0/1
    const int wk   = w & 1;         // k-half: 0/1
    const int q0   = blockIdx.x * 64;
    const int bh   = blockIdx.y;
    const int h    = bh % H_;
    const int b    = bh / H_;
    const size_t base  = (size_t)bh * L_ * D_;
    const size_t vbase = (size_t)bh * D_ * L_;
    const int qbase = q0 + wq * 32;

    const float FMAX = expf(fminf(sml[h], MAXLOG)) + 8.0f;

    // Q fragments, held in registers for the whole sweep.
    // B-frag of 16x16x32: col = q (lane&15), k-dim d = ks*32 + quad*8 + 0..7.
    bf16x8 qf[2][2];
    #pragma unroll
    for (int qt = 0; qt < 2; ++qt)
        #pragma unroll
        for (int ks = 0; ks < 2; ++ks)
            qf[qt][ks] = *(const bf16x8*)&q[base + (size_t)(qbase + qt*16 + c) * D_ + ks*32 + quad*8];

    f32x4 o[4][2];                  // O^T tiles: [dt][qt], row d = dt*16+4*quad+reg, col q
    #pragma unroll
    for (int dt = 0; dt < 4; ++dt)
        #pragma unroll
        for (int qt = 0; qt < 2; ++qt) o[dt][qt] = (f32x4){0.f,0.f,0.f,0.f};
    float l_acc[2] = {0.f, 0.f};

    const int kstart = wk << 10;    // wk * 1024

    bf16x8 kf[2][2][2];   // [buf][s][ks]  A-frag K: row k_kv = 16s+c, d = 32*ks+8*quad+0..7
    bf16x4 vf[2][2][4];   // [buf][s][dt]  A-frag V^T: row d = dt*16+c, k = 16s+4*quad+0..3
    f32x4  bb[2][2][2];   // [buf][s][qt]  bias as S^T C-operand: row k = 16s+4*quad+reg, col q

#define LOADT(BUF, KT) do {                                                             \
    _Pragma("unroll") for (int s = 0; s < 2; ++s) {                                     \
      _Pragma("unroll") for (int ks = 0; ks < 2; ++ks)                                  \
        kf[BUF][s][ks] = *(const bf16x8*)&k[base + (size_t)((KT) + 16*s + c) * D_ + ks*32 + quad*8]; \
      _Pragma("unroll") for (int dt = 0; dt < 4; ++dt)                                  \
        vf[BUF][s][dt] = *(const bf16x4*)&vt[vbase + (size_t)(dt*16 + c) * L_ + (KT) + 16*s + 4*quad]; \
      _Pragma("unroll") for (int qt = 0; qt < 2; ++qt)                                  \
        bb[BUF][s][qt] = *(const f32x4*)&bias[(size_t)(qbase + qt*16 + c) * L_ + (KT) + 16*s + 4*quad]; \
    } } while (0)

#define STEP(BUF, NBUF, KTN) do {                                                       \
    f32x4 st[2][2];                                                                     \
    _Pragma("unroll") for (int s = 0; s < 2; ++s)                                       \
      _Pragma("unroll") for (int qt = 0; qt < 2; ++qt) {                                \
        st[s][qt] = __builtin_amdgcn_mfma_f32_16x16x32_bf16(kf[BUF][s][0], qf[qt][0], bb[BUF][s][qt], 0, 0, 0); \
        st[s][qt] = __builtin_amdgcn_mfma_f32_16x16x32_bf16(kf[BUF][s][1], qf[qt][1], st[s][qt], 0, 0, 0);      \
      }                                                                                 \
    LOADT(NBUF, KTN);                                                                   \
    bf16x4 pf[2][2];                                                                    \
    _Pragma("unroll") for (int s = 0; s < 2; ++s)                                       \
      _Pragma("unroll") for (int qt = 0; qt < 2; ++qt)                                  \
        _Pragma("unroll") for (int r = 0; r < 4; ++r) {                                 \
          const float pv = __expf(st[s][qt][r] - FMAX);                                 \
          l_acc[qt] += pv;                                                              \
          pf[s][qt][r] = (bf16)pv;                                                      \
        }                                                                               \
    _Pragma("unroll") for (int s = 0; s < 2; ++s)                                       \
      _Pragma("unroll") for (int dt = 0; dt < 4; ++dt)                                  \
        _Pragma("unroll") for (int qt = 0; qt < 2; ++qt)                                \
          o[dt][qt] = mfma16(vf[BUF][s][dt], pf[s][qt], o[dt][qt]);                     \
  } while (0)

    LOADT(0, kstart);
    for (int it = 0; it < 16; ++it) {
        const int kt = kstart + it * 64;
        STEP(0, 1, kt + 32);
        STEP(1, 0, (it == 15) ? kstart : (kt + 64));   // last prefetch is a harmless in-range dummy
    }
#undef STEP
#undef LOADT

    // in-wave k reduction of l across quads (quads hold disjoint k rows)
    float lt[2];
    #pragma unroll
    for (int qt = 0; qt < 2; ++qt) {
        float s = l_acc[qt];
        s += __shfl_xor(s, 16);
        s += __shfl_xor(s, 32);
        lt[qt] = s;
    }

    // merge the two k-halves of each q-half through LDS (single barrier)
    if (wk == 1) {
        #pragma unroll
        for (int dt = 0; dt < 4; ++dt)
            #pragma unroll
            for (int qt = 0; qt < 2; ++qt)
                *(f32x4*)&OfT[wq][dt][qt][lane][0] = o[dt][qt];
        if (quad == 0) {
            lfs[wq][0][c] = lt[0];
            lfs[wq][1][c] = lt[1];
        }
    }
    __syncthreads();
    if (wk == 0) {
        #pragma unroll
        for (int qt = 0; qt < 2; ++qt) {
            const float linv = 1.0f / (lt[qt] + lfs[wq][qt][c]);
            const size_t obase = ((size_t)(b * L_ + qbase + qt*16 + c)) * C_ + h * 64;
            #pragma unroll
            for (int dt = 0; dt < 4; ++dt) {
                const f32x4 m = *(const f32x4*)&OfT[wq][dt][qt][lane][0];
                bf16x4 hv, lv;
                #pragma unroll
                for (int r = 0; r < 4; ++r) {
                    const float v = (o[dt][qt][r] + m[r]) * linv;
                    hv[r] = (bf16)v;
                    lv[r] = (bf16)(v - (float)hv[r]);
                }
                *(bf16x4*)&aoh[obase + dt*16 + 4*quad] = hv;
                *(bf16x4*)&aol[obase + dt*16 + 4*quad] = lv;
            }
        }
    }
}

// ---------------------------------------------------------------------------
// Kernel 3: projection GEMM (unchanged).
// ---------------------------------------------------------------------------
__global__ __launch_bounds__(256) void proj_mfma(
    const bf16* __restrict__ Ahg, const bf16* __restrict__ Alg,
    const bf16* __restrict__ Whg, const bf16* __restrict__ Wlg,
    const float* __restrict__ bias, float* __restrict__ outp)
{
    __shared__ __align__(16) bf16 Ah[64][72];
    __shared__ __align__(16) bf16 Al[64][72];
    __shared__ __align__(16) bf16 Bh[64][72];
    __shared__ __align__(16) bf16 Bl[64][72];

    const int t    = threadIdx.x;
    const int w    = t >> 6;
    const int lane = t & 63;
    const int quad = lane >> 4;
    const int c    = lane & 15;
    const int m0   = blockIdx.x * 64;
    const int n0   = blockIdx.y * 64;

    const int r0 = t >> 3;
    const int cg = (t & 7) * 8;

    f32x4 acc[4];
    #pragma unroll
    for (int nt = 0; nt < 4; ++nt) acc[nt] = (f32x4){0.f,0.f,0.f,0.f};

    bf16x8 ahreg[2], alreg[2], bhreg[2], blreg[2];
    #pragma unroll
    for (int p = 0; p < 2; ++p) {
        ahreg[p] = *(const bf16x8*)&Ahg[(size_t)(m0 + r0 + 32 * p) * C_ + cg];
        alreg[p] = *(const bf16x8*)&Alg[(size_t)(m0 + r0 + 32 * p) * C_ + cg];
        bhreg[p] = *(const bf16x8*)&Whg[(size_t)(n0 + r0 + 32 * p) * C_ + cg];
        blreg[p] = *(const bf16x8*)&Wlg[(size_t)(n0 + r0 + 32 * p) * C_ + cg];
    }

    for (int kt = 0; kt < C_; kt += 64) {
        __syncthreads();
        #pragma unroll
        for (int p = 0; p < 2; ++p) {
            *(bf16x8*)&Ah[r0 + 32 * p][cg] = ahreg[p];
            *(bf16x8*)&Al[r0 + 32 * p][cg] = alreg[p];
            *(bf16x8*)&Bh[r0 + 32 * p][cg] = bhreg[p];
            *(bf16x8*)&Bl[r0 + 32 * p][cg] = blreg[p];
        }

        const int kt2 = kt + 64;
        if (kt2 < C_) {
            #pragma unroll
            for (int p = 0; p < 2; ++p) {
                ahreg[p] = *(const bf16x8*)&Ahg[(size_t)(m0 + r0 + 32 * p) * C_ + kt2 + cg];
                alreg[p] = *(const bf16x8*)&Alg[(size_t)(m0 + r0 + 32 * p) * C_ + kt2 + cg];
                bhreg[p] = *(const bf16x8*)&Whg[(size_t)(n0 + r0 + 32 * p) * C_ + kt2 + cg];
                blreg[p] = *(const bf16x8*)&Wlg[(size_t)(n0 + r0 + 32 * p) * C_ + kt2 + cg];
            }
        }
        __syncthreads();

        #pragma unroll
        for (int ks = 0; ks < 2; ++ks) {
            const bf16x8 ah = *(const bf16x8*)&Ah[w * 16 + c][ks * 32 + quad * 8];
            const bf16x8 al = *(const bf16x8*)&Al[w * 16 + c][ks * 32 + quad * 8];
            #pragma unroll
            for (int nt = 0; nt < 4; ++nt) {
                const bf16x8 bh = *(const bf16x8*)&Bh[nt * 16 + c][ks * 32 + quad * 8];
                const bf16x8 bl = *(const bf16x8*)&Bl[nt * 16 + c][ks * 32 + quad * 8];
                acc[nt] = __builtin_amdgcn_mfma_f32_16x16x32_bf16(ah, bh, acc[nt], 0, 0, 0);
                acc[nt] = __builtin_amdgcn_mfma_f32_16x16x32_bf16(ah, bl, acc[nt], 0, 0, 0);
                acc[nt] = __builtin_amdgcn_mfma_f32_16x16x32_bf16(al, bh, acc[nt], 0, 0, 0);
            }
        }
    }

    #pragma unroll
    for (int nt = 0; nt < 4; ++nt) {
        const int col = n0 + nt * 16 + c;
        const float bb = bias[col];
        #pragma unroll
        for (int reg = 0; reg < 4; ++reg) {
            const int row = m0 + w * 16 + quad * 4 + reg;
            outp[(size_t)row * C_ + col] = acc[nt][reg] + bb;
        }
    }
}

// ---------------------------------------------------------------------------
extern "C" void kernel_launch(void* const* d_in, const int* in_sizes, int n_in,
                              void* d_out, int out_size, void* d_ws, size_t ws_size,
                              hipStream_t stream)
{
    const float* x         = (const float*)d_in[0];
    const float* attn_bias = (const float*)d_in[1];
    const float* W_qkv     = (const float*)d_in[2];
    const float* b_qkv     = (const float*)d_in[3];
    const float* sml       = (const float*)d_in[4];
    const float* W_proj    = (const float*)d_in[5];
    const float* b_proj    = (const float*)d_in[6];
    float* out = (float*)d_out;

    // ws layout (bf16 elements): qb,kb,vtb | aoh,aol | Wh,Wl | xb | wqb
    bf16* qb  = (bf16*)d_ws;
    bf16* kb  = qb  + SZ_;
    bf16* vtb = kb  + SZ_;
    bf16* aoh = vtb + SZ_;
    bf16* aol = aoh + MC_;
    bf16* Wh  = aol + MC_;
    bf16* Wl  = Wh  + WP_;
    bf16* xb  = Wl  + WP_;
    bf16* wqb = xb  + MC_;

    // 0) fused prep: cvt x/W_qkv to bf16, split W_proj (no dead zero-fill)
    prep<<<2048, 256, 0, stream>>>(
        (const float4*)x, (const float4*)W_qkv, (const float4*)W_proj,
        xb, wqb, Wh, Wl);

    // 1) QKV GEMM (bf16 MFMA, fused l2norm+scale, prefetch)
    qkv_mfma<<<dim3(M_ / 128, (3 * C_) / 64), 256, 0, stream>>>(
        xb, wqb, b_qkv, sml, qb, kb, vtb);

    // 2) flash attention v6: barrier-free main loop, swapped-QK + K=16 PV
    flash_mfma<<<dim3(L_ / 64, B_ * H_), 256, 0, stream>>>(
        qb, kb, vtb, attn_bias, sml, aoh, aol);

    // 3) projection GEMM (hi/lo split MFMA, BM=64, 768 blocks, prefetch)
    proj_mfma<<<dim3(M_ / 64, C_ / 64), 256, 0, stream>>>(
        aoh, aol, Wh, Wl, b_proj, out);
}

// Round 2
// 200.831 us; speedup vs baseline: 1.5407x; 1.5407x over previous
//
#include <hip/hip_runtime.h>
#include <math.h>

#define B_ 2
#define L_ 2048
#define C_ 768
#define H_ 12
#define D_ 64
#define M_ (B_ * L_)          // 4096
#define MAXLOG 4.605170185988091f   // log(100)

typedef __bf16 bf16;
typedef __bf16 bf16x4 __attribute__((ext_vector_type(4)));
typedef __bf16 bf16x8 __attribute__((ext_vector_type(8)));
typedef float  f32x4  __attribute__((ext_vector_type(4)));
typedef short  s16x4  __attribute__((ext_vector_type(4)));

// workspace element counts
#define SZ_  ((size_t)B_ * H_ * L_ * D_)   // 3,145,728 (q,k,vt each)
#define MC_  ((size_t)M_ * C_)             // 3,145,728 (x / ao)
#define WQ_  ((size_t)3 * C_ * C_)         // 1,769,472 (W_qkv)
#define WP_  ((size_t)C_ * C_)             //   589,824 (W_proj)

// K=16 bf16 MFMA. S^T accumulator layout (row=4*quad+reg, col=lane&15) equals
// this op's B-fragment layout, so P^T feeds PV directly from registers.
static __device__ __forceinline__ f32x4 mfma16(bf16x4 a, bf16x4 b, f32x4 c) {
#if __has_builtin(__builtin_amdgcn_mfma_f32_16x16x16_bf16)
    return __builtin_amdgcn_mfma_f32_16x16x16_bf16(a, b, c, 0, 0, 0);
#elif __has_builtin(__builtin_amdgcn_mfma_f32_16x16x16bf16_1k)
    return __builtin_amdgcn_mfma_f32_16x16x16bf16_1k(*(s16x4*)&a, *(s16x4*)&b, c, 0, 0, 0);
#else
    f32x4 d;
    asm("v_mfma_f32_16x16x16_bf16 %0, %1, %2, %3" : "=v"(d) : "v"(a), "v"(b), "v"(c));
    return d;
#endif
}

// ---------------------------------------------------------------------------
// Kernel 0: fused prep (no dead zero-fill — qb..aol fully overwritten later).
// ---------------------------------------------------------------------------
__global__ __launch_bounds__(256) void prep(
    const float4* __restrict__ x, const float4* __restrict__ Wq,
    const float4* __restrict__ Wp,
    bf16* __restrict__ xb, bf16* __restrict__ wqb,
    bf16* __restrict__ Wh, bf16* __restrict__ Wl)
{
    const int X4 = (int)(MC_ / 4);
    const int W4 = (int)(WQ_ / 4);
    const int S4 = (int)(WP_ / 4);
    const int total = X4 + W4 + S4;

    const int i0 = blockIdx.x * 256 + threadIdx.x;
    const int stride = gridDim.x * 256;
    for (int i = i0; i < total; i += stride) {
        if (i < X4) {
            const float4 v = x[i];
            bf16x4 o; o[0]=(bf16)v.x; o[1]=(bf16)v.y; o[2]=(bf16)v.z; o[3]=(bf16)v.w;
            *(bf16x4*)&xb[(size_t)i * 4] = o;
        } else if (i < X4 + W4) {
            const int j = i - X4;
            const float4 v = Wq[j];
            bf16x4 o; o[0]=(bf16)v.x; o[1]=(bf16)v.y; o[2]=(bf16)v.z; o[3]=(bf16)v.w;
            *(bf16x4*)&wqb[(size_t)j * 4] = o;
        } else {
            const int j = i - X4 - W4;
            const float4 v = Wp[j];
            bf16x4 h, l;
            h[0]=(bf16)v.x; l[0]=(bf16)(v.x-(float)h[0]);
            h[1]=(bf16)v.y; l[1]=(bf16)(v.y-(float)h[1]);
            h[2]=(bf16)v.z; l[2]=(bf16)(v.z-(float)h[2]);
            h[3]=(bf16)v.w; l[3]=(bf16)(v.w-(float)h[3]);
            *(bf16x4*)&Wh[(size_t)j * 4] = h;
            *(bf16x4*)&Wl[(size_t)j * 4] = l;
        }
    }
}

// ---------------------------------------------------------------------------
// Kernel 1: QKV GEMM (unchanged).
// ---------------------------------------------------------------------------
__global__ __launch_bounds__(256) void qkv_mfma(
    const bf16* __restrict__ A, const bf16* __restrict__ W,
    const float* __restrict__ bias, const float* __restrict__ sml,
    bf16* __restrict__ qb, bf16* __restrict__ kb, bf16* __restrict__ vtb)
{
    __shared__ __align__(16) bf16 As[128][72];
    __shared__ __align__(16) bf16 Bs[64][72];

    const int t    = threadIdx.x;
    const int w    = t >> 6;
    const int lane = t & 63;
    const int quad = lane >> 4;
    const int c    = lane & 15;
    const int m0   = blockIdx.x * 128;
    const int n0   = blockIdx.y * 64;

    const int r0 = t >> 3;
    const int cg = (t & 7) * 8;

    f32x4 acc[2][4];
    #pragma unroll
    for (int mt = 0; mt < 2; ++mt)
        #pragma unroll
        for (int nt = 0; nt < 4; ++nt) acc[mt][nt] = (f32x4){0.f,0.f,0.f,0.f};

    bf16x8 areg[4], breg[2];
    #pragma unroll
    for (int p = 0; p < 4; ++p)
        areg[p] = *(const bf16x8*)&A[(size_t)(m0 + r0 + 32 * p) * C_ + cg];
    #pragma unroll
    for (int p = 0; p < 2; ++p)
        breg[p] = *(const bf16x8*)&W[(size_t)(n0 + r0 + 32 * p) * C_ + cg];

    for (int kt = 0; kt < C_; kt += 64) {
        __syncthreads();
        #pragma unroll
        for (int p = 0; p < 4; ++p) *(bf16x8*)&As[r0 + 32 * p][cg] = areg[p];
        #pragma unroll
        for (int p = 0; p < 2; ++p) *(bf16x8*)&Bs[r0 + 32 * p][cg] = breg[p];

        const int kt2 = kt + 64;
        if (kt2 < C_) {
            #pragma unroll
            for (int p = 0; p < 4; ++p)
                areg[p] = *(const bf16x8*)&A[(size_t)(m0 + r0 + 32 * p) * C_ + kt2 + cg];
            #pragma unroll
            for (int p = 0; p < 2; ++p)
                breg[p] = *(const bf16x8*)&W[(size_t)(n0 + r0 + 32 * p) * C_ + kt2 + cg];
        }
        __syncthreads();

        #pragma unroll
        for (int ks = 0; ks < 2; ++ks) {
            #pragma unroll
            for (int mt = 0; mt < 2; ++mt) {
                const bf16x8 a = *(const bf16x8*)&As[w * 32 + mt * 16 + c][ks * 32 + quad * 8];
                #pragma unroll
                for (int nt = 0; nt < 4; ++nt) {
                    const bf16x8 b = *(const bf16x8*)&Bs[nt * 16 + c][ks * 32 + quad * 8];
                    acc[mt][nt] = __builtin_amdgcn_mfma_f32_16x16x32_bf16(a, b, acc[mt][nt], 0, 0, 0);
                }
            }
        }
    }

    const int three = blockIdx.y / H_;
    const int h     = blockIdx.y % H_;
    const int bidx  = m0 >> 11;
    const int l0    = (m0 & (L_ - 1)) + w * 32;

    if (three < 2) {
        bf16* dst = (three == 0) ? qb : kb;
        const float scale = (three == 0) ? expf(fminf(sml[h], MAXLOG)) : 1.0f;
        #pragma unroll
        for (int mt = 0; mt < 2; ++mt) {
            float val[4][4];
            float ss[4] = {0.f, 0.f, 0.f, 0.f};
            #pragma unroll
            for (int nt = 0; nt < 4; ++nt) {
                const float bb = bias[n0 + nt * 16 + c];
                #pragma unroll
                for (int reg = 0; reg < 4; ++reg) {
                    const float v = acc[mt][nt][reg] + bb;
                    val[nt][reg] = v;
                    ss[reg] += v * v;
                }
            }
            #pragma unroll
            for (int reg = 0; reg < 4; ++reg) {
                float s = ss[reg];
                #pragma unroll
                for (int off = 1; off < 16; off <<= 1) s += __shfl_xor(s, off, 16);
                const float inv = scale / fmaxf(sqrtf(s), 1e-12f);
                const int l = l0 + mt * 16 + quad * 4 + reg;
                #pragma unroll
                for (int nt = 0; nt < 4; ++nt)
                    dst[((size_t)(bidx * H_ + h) * L_ + l) * D_ + nt * 16 + c] =
                        (bf16)(val[nt][reg] * inv);
            }
        }
    } else {
        #pragma unroll
        for (int mt = 0; mt < 2; ++mt)
            #pragma unroll
            for (int nt = 0; nt < 4; ++nt) {
                const int d = nt * 16 + c;
                const float bb = bias[n0 + d];
                const int l = l0 + mt * 16 + quad * 4;
                bf16x4 o;
                #pragma unroll
                for (int reg = 0; reg < 4; ++reg) o[reg] = (bf16)(acc[mt][nt][reg] + bb);
                *(bf16x4*)&vtb[((size_t)(bidx * H_ + h) * D_ + d) * L_ + l] = o;
            }
    }
}

// ---------------------------------------------------------------------------
// Kernel 2: flash attention v7.
//   v5's coalesced staged memory pipeline + v6's verified in-register softmax:
//   - K/V staged global->reg->LDS (double-buffered), ONE barrier per 64-k tile
//   - S^T = K·Q^T with bias as MFMA C operand (float4 bias loads)
//   - exp in-register; P^T accumulator == B-frag of K=16 PV MFMA (no P LDS)
//   - Q in registers for the whole sweep (no Q LDS buffer)
//   Each wave owns 16 q rows; all waves share the staged k-tile.
// ---------------------------------------------------------------------------
__global__ __launch_bounds__(256, 3) void flash_mfma(
    const bf16* __restrict__ q, const bf16* __restrict__ k,
    const bf16* __restrict__ vt, const float* __restrict__ bias,
    const float* __restrict__ sml,
    bf16* __restrict__ aoh, bf16* __restrict__ aol)
{
    __shared__ __align__(16) bf16 Ks0 [64][72];
    __shared__ __align__(16) bf16 Vts0[64][72];
    __shared__ __align__(16) bf16 Ks1 [64][72];
    __shared__ __align__(16) bf16 Vts1[64][72];

    const int t    = threadIdx.x;
    const int w    = t >> 6;
    const int lane = t & 63;
    const int quad = lane >> 4;
    const int c    = lane & 15;
    const int q0   = blockIdx.x * 64;
    const int bh   = blockIdx.y;
    const int h    = bh % H_;
    const int b    = bh / H_;
    const size_t base  = (size_t)bh * L_ * D_;
    const size_t vbase = (size_t)bh * D_ * L_;
    const int qrow = q0 + w * 16 + c;      // this lane's q index (column of S^T)

    const float FMAX = expf(fminf(sml[h], MAXLOG)) + 8.0f;

    // Q B-fragments straight from global, held for the whole sweep.
    bf16x8 qf[2];
    qf[0] = *(const bf16x8*)&q[base + (size_t)qrow * D_ + quad * 8];
    qf[1] = *(const bf16x8*)&q[base + (size_t)qrow * D_ + 32 + quad * 8];

    // staging indices (v5 pattern, coalesced)
    const int r0  = t >> 3,         c00 = (t & 7) * 8;
    const int r1  = (t + 256) >> 3, c01 = ((t + 256) & 7) * 8;

    float l_acc = 0.f;
    f32x4 o[4];
    #pragma unroll
    for (int dt = 0; dt < 4; ++dt) o[dt] = (f32x4){0.f, 0.f, 0.f, 0.f};

    bf16x8 kreg[2], vreg[2];
    f32x4  bregA[4], bregB[4];

    // prologue: tile 0 -> regs -> LDS buf0; tile 1 -> regs; bias 0/1 -> regs
    kreg[0] = *(const bf16x8*)&k [base  + (size_t)r0 * D_ + c00];
    kreg[1] = *(const bf16x8*)&k [base  + (size_t)r1 * D_ + c01];
    vreg[0] = *(const bf16x8*)&vt[vbase + (size_t)r0 * L_ + c00];
    vreg[1] = *(const bf16x8*)&vt[vbase + (size_t)r1 * L_ + c01];
    #pragma unroll
    for (int s = 0; s < 4; ++s)
        bregA[s] = *(const f32x4*)&bias[(size_t)qrow * L_ + 16 * s + 4 * quad];

    *(bf16x8*)&Ks0 [r0][c00] = kreg[0];
    *(bf16x8*)&Ks0 [r1][c01] = kreg[1];
    *(bf16x8*)&Vts0[r0][c00] = vreg[0];
    *(bf16x8*)&Vts0[r1][c01] = vreg[1];

    kreg[0] = *(const bf16x8*)&k [base  + (size_t)(64 + r0) * D_ + c00];
    kreg[1] = *(const bf16x8*)&k [base  + (size_t)(64 + r1) * D_ + c01];
    vreg[0] = *(const bf16x8*)&vt[vbase + (size_t)r0 * L_ + 64 + c00];
    vreg[1] = *(const bf16x8*)&vt[vbase + (size_t)r1 * L_ + 64 + c01];
    #pragma unroll
    for (int s = 0; s < 4; ++s)
        bregB[s] = *(const f32x4*)&bias[(size_t)qrow * L_ + 64 + 16 * s + 4 * quad];
    __syncthreads();

// One 64-k tile: stage tile IT+1 from regs, prefetch tile IT+2 into regs,
// compute tile IT, single barrier at the end.
#define FSTEP(KS_C, VT_C, KS_N, VT_N, BC, IT) do {                               \
    if ((IT) + 1 < 32) {                                                         \
        *(bf16x8*)&KS_N [r0][c00] = kreg[0];                                     \
        *(bf16x8*)&KS_N [r1][c01] = kreg[1];                                     \
        *(bf16x8*)&VT_N [r0][c00] = vreg[0];                                     \
        *(bf16x8*)&VT_N [r1][c01] = vreg[1];                                     \
    }                                                                            \
    f32x4 st[4];                                                                 \
    _Pragma("unroll") for (int s = 0; s < 4; ++s) st[s] = BC[s];                 \
    if ((IT) + 2 < 32) {                                                         \
        const int kp = ((IT) + 2) * 64;                                          \
        kreg[0] = *(const bf16x8*)&k [base  + (size_t)(kp + r0) * D_ + c00];     \
        kreg[1] = *(const bf16x8*)&k [base  + (size_t)(kp + r1) * D_ + c01];     \
        vreg[0] = *(const bf16x8*)&vt[vbase + (size_t)r0 * L_ + kp + c00];       \
        vreg[1] = *(const bf16x8*)&vt[vbase + (size_t)r1 * L_ + kp + c01];       \
        _Pragma("unroll") for (int s = 0; s < 4; ++s)                            \
            BC[s] = *(const f32x4*)&bias[(size_t)qrow * L_ + kp + 16*s + 4*quad];\
    }                                                                            \
    _Pragma("unroll") for (int ks = 0; ks < 2; ++ks)                             \
        _Pragma("unroll") for (int s = 0; s < 4; ++s) {                          \
            const bf16x8 kf = *(const bf16x8*)&KS_C[s*16 + c][ks*32 + quad*8];   \
            st[s] = __builtin_amdgcn_mfma_f32_16x16x32_bf16(kf, qf[ks], st[s], 0, 0, 0); \
        }                                                                        \
    bf16x4 pf[4];                                                                \
    _Pragma("unroll") for (int s = 0; s < 4; ++s)                                \
        _Pragma("unroll") for (int r = 0; r < 4; ++r) {                          \
            const float pv = __expf(st[s][r] - FMAX);                            \
            l_acc += pv;                                                         \
            pf[s][r] = (bf16)pv;                                                 \
        }                                                                        \
    _Pragma("unroll") for (int s = 0; s < 4; ++s)                                \
        _Pragma("unroll") for (int dt = 0; dt < 4; ++dt) {                       \
            const bf16x4 vfr = *(const bf16x4*)&VT_C[dt*16 + c][16*s + 4*quad];  \
            o[dt] = mfma16(vfr, pf[s], o[dt]);                                   \
        }                                                                        \
    __syncthreads();                                                             \
} while (0)

    for (int it = 0; it < 32; it += 2) {
        FSTEP(Ks0, Vts0, Ks1, Vts1, bregA, it);
        FSTEP(Ks1, Vts1, Ks0, Vts0, bregB, it + 1);
    }
#undef FSTEP

    // l: lane holds k-rows 4*quad+0..3 of every tile; reduce across quads.
    float rs = l_acc;
    rs += __shfl_xor(rs, 16);
    rs += __shfl_xor(rs, 32);
    const float linv = 1.0f / rs;

    const size_t obase = ((size_t)(b * L_ + qrow)) * C_ + h * 64;
    #pragma unroll
    for (int dt = 0; dt < 4; ++dt) {
        bf16x4 hv, lv;
        #pragma unroll
        for (int r = 0; r < 4; ++r) {
            const float v = o[dt][r] * linv;
            hv[r] = (bf16)v;
            lv[r] = (bf16)(v - (float)hv[r]);
        }
        *(bf16x4*)&aoh[obase + dt * 16 + 4 * quad] = hv;
        *(bf16x4*)&aol[obase + dt * 16 + 4 * quad] = lv;
    }
}

// ---------------------------------------------------------------------------
// Kernel 3: projection GEMM (unchanged).
// ---------------------------------------------------------------------------
__global__ __launch_bounds__(256) void proj_mfma(
    const bf16* __restrict__ Ahg, const bf16* __restrict__ Alg,
    const bf16* __restrict__ Whg, const bf16* __restrict__ Wlg,
    const float* __restrict__ bias, float* __restrict__ outp)
{
    __shared__ __align__(16) bf16 Ah[64][72];
    __shared__ __align__(16) bf16 Al[64][72];
    __shared__ __align__(16) bf16 Bh[64][72];
    __shared__ __align__(16) bf16 Bl[64][72];

    const int t    = threadIdx.x;
    const int w    = t >> 6;
    const int lane = t & 63;
    const int quad = lane >> 4;
    const int c    = lane & 15;
    const int m0   = blockIdx.x * 64;
    const int n0   = blockIdx.y * 64;

    const int r0 = t >> 3;
    const int cg = (t & 7) * 8;

    f32x4 acc[4];
    #pragma unroll
    for (int nt = 0; nt < 4; ++nt) acc[nt] = (f32x4){0.f,0.f,0.f,0.f};

    bf16x8 ahreg[2], alreg[2], bhreg[2], blreg[2];
    #pragma unroll
    for (int p = 0; p < 2; ++p) {
        ahreg[p] = *(const bf16x8*)&Ahg[(size_t)(m0 + r0 + 32 * p) * C_ + cg];
        alreg[p] = *(const bf16x8*)&Alg[(size_t)(m0 + r0 + 32 * p) * C_ + cg];
        bhreg[p] = *(const bf16x8*)&Whg[(size_t)(n0 + r0 + 32 * p) * C_ + cg];
        blreg[p] = *(const bf16x8*)&Wlg[(size_t)(n0 + r0 + 32 * p) * C_ + cg];
    }

    for (int kt = 0; kt < C_; kt += 64) {
        __syncthreads();
        #pragma unroll
        for (int p = 0; p < 2; ++p) {
            *(bf16x8*)&Ah[r0 + 32 * p][cg] = ahreg[p];
            *(bf16x8*)&Al[r0 + 32 * p][cg] = alreg[p];
            *(bf16x8*)&Bh[r0 + 32 * p][cg] = bhreg[p];
            *(bf16x8*)&Bl[r0 + 32 * p][cg] = blreg[p];
        }

        const int kt2 = kt + 64;
        if (kt2 < C_) {
            #pragma unroll
            for (int p = 0; p < 2; ++p) {
                ahreg[p] = *(const bf16x8*)&Ahg[(size_t)(m0 + r0 + 32 * p) * C_ + kt2 + cg];
                alreg[p] = *(const bf16x8*)&Alg[(size_t)(m0 + r0 + 32 * p) * C_ + kt2 + cg];
                bhreg[p] = *(const bf16x8*)&Whg[(size_t)(n0 + r0 + 32 * p) * C_ + kt2 + cg];
                blreg[p] = *(const bf16x8*)&Wlg[(size_t)(n0 + r0 + 32 * p) * C_ + kt2 + cg];
            }
        }
        __syncthreads();

        #pragma unroll
        for (int ks = 0; ks < 2; ++ks) {
            const bf16x8 ah = *(const bf16x8*)&Ah[w * 16 + c][ks * 32 + quad * 8];
            const bf16x8 al = *(const bf16x8*)&Al[w * 16 + c][ks * 32 + quad * 8];
            #pragma unroll
            for (int nt = 0; nt < 4; ++nt) {
                const bf16x8 bh = *(const bf16x8*)&Bh[nt * 16 + c][ks * 32 + quad * 8];
                const bf16x8 bl = *(const bf16x8*)&Bl[nt * 16 + c][ks * 32 + quad * 8];
                acc[nt] = __builtin_amdgcn_mfma_f32_16x16x32_bf16(ah, bh, acc[nt], 0, 0, 0);
                acc[nt] = __builtin_amdgcn_mfma_f32_16x16x32_bf16(ah, bl, acc[nt], 0, 0, 0);
                acc[nt] = __builtin_amdgcn_mfma_f32_16x16x32_bf16(al, bh, acc[nt], 0, 0, 0);
            }
        }
    }

    #pragma unroll
    for (int nt = 0; nt < 4; ++nt) {
        const int col = n0 + nt * 16 + c;
        const float bb = bias[col];
        #pragma unroll
        for (int reg = 0; reg < 4; ++reg) {
            const int row = m0 + w * 16 + quad * 4 + reg;
            outp[(size_t)row * C_ + col] = acc[nt][reg] + bb;
        }
    }
}

// ---------------------------------------------------------------------------
extern "C" void kernel_launch(void* const* d_in, const int* in_sizes, int n_in,
                              void* d_out, int out_size, void* d_ws, size_t ws_size,
                              hipStream_t stream)
{
    const float* x         = (const float*)d_in[0];
    const float* attn_bias = (const float*)d_in[1];
    const float* W_qkv     = (const float*)d_in[2];
    const float* b_qkv     = (const float*)d_in[3];
    const float* sml       = (const float*)d_in[4];
    const float* W_proj    = (const float*)d_in[5];
    const float* b_proj    = (const float*)d_in[6];
    float* out = (float*)d_out;

    // ws layout (bf16 elements): qb,kb,vtb | aoh,aol | Wh,Wl | xb | wqb
    bf16* qb  = (bf16*)d_ws;
    bf16* kb  = qb  + SZ_;
    bf16* vtb = kb  + SZ_;
    bf16* aoh = vtb + SZ_;
    bf16* aol = aoh + MC_;
    bf16* Wh  = aol + MC_;
    bf16* Wl  = Wh  + WP_;
    bf16* xb  = Wl  + WP_;
    bf16* wqb = xb  + MC_;

    // 0) fused prep
    prep<<<2048, 256, 0, stream>>>(
        (const float4*)x, (const float4*)W_qkv, (const float4*)W_proj,
        xb, wqb, Wh, Wl);

    // 1) QKV GEMM
    qkv_mfma<<<dim3(M_ / 128, (3 * C_) / 64), 256, 0, stream>>>(
        xb, wqb, b_qkv, sml, qb, kb, vtb);

    // 2) flash attention v7: staged LDS + in-register softmax, 1 barrier/tile
    flash_mfma<<<dim3(L_ / 64, B_ * H_), 256, 0, stream>>>(
        qb, kb, vtb, attn_bias, sml, aoh, aol);

    // 3) projection GEMM
    proj_mfma<<<dim3(M_ / 64, C_ / 64), 256, 0, stream>>>(
        aoh, aol, Wh, Wl, b_proj, out);
}